// Round 12
// baseline (197.175 us; speedup 1.0000x reference)
//
#include <hip/hip_runtime.h>
#include <math.h>

#define NROWS 32768
#define CDIM  512
#define G_    2
#define V_    320
#define NCOLS 640
#define DCODE 128
#define NSLOT 64
#define BMR   32   // rows per block

typedef short bf16x8 __attribute__((ext_vector_type(8)));
typedef float f32x4  __attribute__((ext_vector_type(4)));

__device__ __forceinline__ short f2bf(float f) {
    union { float f; unsigned u; } v; v.f = f;
    unsigned r = v.u + 0x7FFFu + ((v.u >> 16) & 1u);   // RTNE
    return (short)(r >> 16);
}

// W [512][640] f32 -> wpk fragment-packed bf16 (640 KB).
// frag gid = ((g*16+ts)*20 + tt16)*64 + kq*16 + l15, elem e = w[ts*32+kq*8+e][g*320+tt16*16+l15]
__global__ __launch_bounds__(256) void wprep(const float* __restrict__ w,
                                             short* __restrict__ wpk) {
    int gid = blockIdx.x * 256 + threadIdx.x;       // 40960 fragments
    int l15 = gid & 15, kq = (gid >> 4) & 3;
    int rem = gid >> 6;
    int tt16 = rem % 20; rem /= 20;
    int ts = rem & 15, g = rem >> 4;
    int n  = g * V_ + tt16 * 16 + l15;
    int k0 = ts * 32 + kq * 8;
    bf16x8 o;
    #pragma unroll
    for (int e = 0; e < 8; ++e) o[e] = f2bf(w[(size_t)(k0 + e) * NCOLS + n]);
    *(bf16x8*)&wpk[(size_t)gid * 8] = o;
}

// Block = 32 rows x 640 cols, 512 thr = 8 waves; wave cg owns cols cg*80..+80 (g=cg>>2).
// Swapped MFMA: D[n][m] = mfma(Wfrag, Hfrag). H loaded DIRECT from global f32
// (same addresses across all 8 waves -> L1 broadcast), W streamed from L2 wpk with
// 1-ahead prefetch. No K-loop LDS, no K-loop barriers. acc = 5x2xf32x4 = 40 regs.
__global__ __launch_bounds__(512, 4) void gvq_gemm(
    const float* __restrict__ hidden,    // [32768][512] f32
    const float* __restrict__ gumbel_u,  // [65536][320] f32
    const short* __restrict__ wpk,       // fragment-packed bf16
    const float* __restrict__ bias,      // [640]
    const float* __restrict__ cv,        // [640][128]
    float* __restrict__ out,             // [32768][256] + perp scalar
    float* __restrict__ gavg)            // [NSLOT][640]
{
    __shared__ float s_psum[G_][4][BMR];
    __shared__ float s_bestv[G_][4][BMR];
    __shared__ int   s_besti[G_][4][BMR];

    const int t    = threadIdx.x;
    const int wave = t >> 6;
    const int lane = t & 63;
    const int l15  = lane & 15;
    const int kq   = lane >> 4;
    const int cg   = wave;               // col group: 80 cols
    const int g    = cg >> 2;
    const int tb   = (cg & 3) * 5;       // tt16 base within group g
    const int m0   = blockIdx.x * BMR;

    const float* hp0 = hidden + (size_t)(m0 + l15) * CDIM + kq * 8;        // rows mf=0
    const float* hp1 = hp0 + (size_t)16 * CDIM;                            // rows mf=1
    const short* wbase = wpk + ((size_t)(g * 16) * 20 + tb) * 512 + (size_t)lane * 8;

    f32x4 acc[5][2];                     // [nf][mf]
    #pragma unroll
    for (int nf = 0; nf < 5; ++nf)
        #pragma unroll
        for (int mf = 0; mf < 2; ++mf)
            #pragma unroll
            for (int r = 0; r < 4; ++r) acc[nf][mf][r] = 0.f;

    bf16x8 bw[5];
    #pragma unroll
    for (int nf = 0; nf < 5; ++nf) bw[nf] = *(const bf16x8*)(wbase + nf * 512);

    #pragma unroll
    for (int ts = 0; ts < 16; ++ts) {
        const short* wts = wbase + ts * 10240;
        bf16x8 bn[5];
        if (ts < 15) {                   // prefetch W for ts+1
            #pragma unroll
            for (int nf = 0; nf < 5; ++nf)
                bn[nf] = *(const bf16x8*)(wts + 10240 + nf * 512);
        }
        // H fragments, direct from global (L1-broadcast across waves)
        float4 h00 = *(const float4*)(hp0 + ts * 32);
        float4 h01 = *(const float4*)(hp0 + ts * 32 + 4);
        float4 h10 = *(const float4*)(hp1 + ts * 32);
        float4 h11 = *(const float4*)(hp1 + ts * 32 + 4);
        bf16x8 hf0, hf1;
        hf0[0]=f2bf(h00.x); hf0[1]=f2bf(h00.y); hf0[2]=f2bf(h00.z); hf0[3]=f2bf(h00.w);
        hf0[4]=f2bf(h01.x); hf0[5]=f2bf(h01.y); hf0[6]=f2bf(h01.z); hf0[7]=f2bf(h01.w);
        hf1[0]=f2bf(h10.x); hf1[1]=f2bf(h10.y); hf1[2]=f2bf(h10.z); hf1[3]=f2bf(h10.w);
        hf1[4]=f2bf(h11.x); hf1[5]=f2bf(h11.y); hf1[6]=f2bf(h11.z); hf1[7]=f2bf(h11.w);
        #pragma unroll
        for (int nf = 0; nf < 5; ++nf)
            acc[nf][0] = __builtin_amdgcn_mfma_f32_16x16x32_bf16(bw[nf], hf0, acc[nf][0], 0, 0, 0);
        #pragma unroll
        for (int nf = 0; nf < 5; ++nf)
            acc[nf][1] = __builtin_amdgcn_mfma_f32_16x16x32_bf16(bw[nf], hf1, acc[nf][1], 0, 0, 0);
        #pragma unroll
        for (int nf = 0; nf < 5; ++nf) bw[nf] = bn[nf];
    }

    // ---- epilogue (lane owns rows m0+mf*16+l15, cols g*320+(tb+nf)*16+kq*4+r) ----
    float4 bv4[5];
    #pragma unroll
    for (int nf = 0; nf < 5; ++nf)
        bv4[nf] = *(const float4*)&bias[g * V_ + (tb + nf) * 16 + kq * 4];

    #pragma unroll
    for (int mf = 0; mf < 2; ++mf) {
        const int row = m0 + mf * 16 + l15;
        const float* up = gumbel_u + ((size_t)row * G_ + g) * V_;
        float s = 0.f, best = -1e30f; int bi = 0;
        #pragma unroll
        for (int nf = 0; nf < 5; ++nf) {
            float4 u4 = *(const float4*)&up[(tb + nf) * 16 + kq * 4];
            #pragma unroll
            for (int r = 0; r < 4; ++r) {
                float z = fminf(acc[nf][mf][r] + bv4[nf][r], 60.f);
                float e = __expf(z);
                acc[nf][mf][r] = e;                        // keep numerator for cp
                s += e;
                float u = (r == 0) ? u4.x : (r == 1) ? u4.y : (r == 2) ? u4.z : u4.w;
                float wv = -__logf(u + 1e-10f) + 1e-10f;
                float ratio = e * __builtin_amdgcn_rcpf(wv);  // argmax(z+gumbel)==argmax e/wv
                const int vi = (tb + nf) * 16 + kq * 4 + r;   // ascending scan -> first-max
                if (ratio > best) { best = ratio; bi = vi; }
            }
        }
        // reduce across kq groups (cols): lanes l15, l15+16, l15+32, l15+48
        #pragma unroll
        for (int o = 16; o <= 32; o <<= 1) {
            s += __shfl_xor(s, o);
            float ov = __shfl_xor(best, o);
            int   oi = __shfl_xor(bi, o);
            if (ov > best || (ov == best && oi < bi)) { best = ov; bi = oi; }
        }
        if (kq == 0) {                       // lanes 0..15
            s_psum[g][cg & 3][mf * 16 + l15]  = s;
            s_bestv[g][cg & 3][mf * 16 + l15] = best;
            s_besti[g][cg & 3][mf * 16 + l15] = bi;
        }
    }
    __syncthreads();

    // ---- cp: per-lane e*inv summed over its 2 rows, fold l15, atomics (1 per col) ----
    float inv[2];
    #pragma unroll
    for (int mf = 0; mf < 2; ++mf) {
        const int rl = mf * 16 + l15;
        inv[mf] = 1.f / (s_psum[g][0][rl] + s_psum[g][1][rl] +
                         s_psum[g][2][rl] + s_psum[g][3][rl]);
    }
    float cpl[5][4];
    #pragma unroll
    for (int nf = 0; nf < 5; ++nf)
        #pragma unroll
        for (int r = 0; r < 4; ++r) {
            float v = acc[nf][0][r] * inv[0] + acc[nf][1][r] * inv[1];
            #pragma unroll
            for (int o = 1; o <= 8; o <<= 1) v += __shfl_xor(v, o);
            cpl[nf][r] = v;
        }
    float* gslot = gavg + (size_t)(blockIdx.x & (NSLOT - 1)) * NCOLS;
    if (l15 == 0) {
        #pragma unroll
        for (int nf = 0; nf < 5; ++nf)
            #pragma unroll
            for (int r = 0; r < 4; ++r)
                atomicAdd(&gslot[g * V_ + (tb + nf) * 16 + kq * 4 + r], cpl[nf][r]);
    }

    // ---- winner finalize + codevector gather: 64 (row,g) tasks, 8 threads each ----
    {
        const int task = t >> 3;             // 0..63
        const int seg  = t & 7;
        const int r_   = task >> 1, gg = task & 1;
        float best = s_bestv[gg][0][r_]; int bi = s_besti[gg][0][r_];
        #pragma unroll
        for (int q = 1; q < 4; ++q) {
            float v = s_bestv[gg][q][r_];
            if (v > best) { best = v; bi = s_besti[gg][q][r_]; }
        }
        const float* src = cv + ((size_t)gg * V_ + bi) * DCODE + seg * 16;
        float* dst = out + (size_t)(m0 + r_) * (G_ * DCODE) + gg * DCODE + seg * 16;
        #pragma unroll
        for (int j = 0; j < 4; ++j)
            *(float4*)(dst + j * 4) = *(const float4*)(src + j * 4);
    }
}

__global__ __launch_bounds__(64) void gvq_perp(const float* __restrict__ gavg,
                                               float* __restrict__ out, int nslot)
{
    const int lane = threadIdx.x;
    float s0 = 0.f, s1 = 0.f;
    for (int v = lane; v < V_; v += 64) {
        float p0 = 0.f, p1 = 0.f;
        for (int s = 0; s < nslot; ++s) {
            p0 += gavg[(size_t)s * NCOLS + v];
            p1 += gavg[(size_t)s * NCOLS + V_ + v];
        }
        p0 *= (1.f / NROWS); p1 *= (1.f / NROWS);
        s0 += p0 * logf(p0 + 1e-7f);
        s1 += p1 * logf(p1 + 1e-7f);
    }
    #pragma unroll
    for (int o = 32; o >= 1; o >>= 1) {
        s0 += __shfl_xor(s0, o);
        s1 += __shfl_xor(s1, o);
    }
    if (lane == 0)
        out[(size_t)NROWS * (G_ * DCODE)] = expf(-s0) + expf(-s1);
}

extern "C" void kernel_launch(void* const* d_in, const int* in_sizes, int n_in,
                              void* d_out, int out_size, void* d_ws, size_t ws_size,
                              hipStream_t stream)
{
    const float* hidden = (const float*)d_in[0];
    const float* gu     = (const float*)d_in[1];
    const float* w      = (const float*)d_in[2];
    const float* b      = (const float*)d_in[3];
    const float* cv     = (const float*)d_in[4];
    float* out  = (float*)d_out;
    float* gavg = (float*)d_ws;                       // [NSLOT][640] f32 = 160 KB
    short* wpk  = (short*)((char*)d_ws + 163840);     // 640 KB fragment-packed W

    hipMemsetAsync(d_ws, 0, NSLOT * NCOLS * sizeof(float), stream);
    wprep<<<160, 256, 0, stream>>>(w, wpk);
    gvq_gemm<<<NROWS / BMR, 512, 0, stream>>>(hidden, gu, wpk, b, cv, out, gavg);
    gvq_perp<<<1, 64, 0, stream>>>(gavg, out, NSLOT);
}

// Round 13
// 118.267 us; speedup vs baseline: 1.6672x; 1.6672x over previous
//
#include <hip/hip_runtime.h>
#include <math.h>

#define NROWS 32768
#define CDIM  512
#define G_    2
#define V_    320
#define NCOLS 640
#define DCODE 128
#define NSLOT 64
#define BMR   32   // rows per block

typedef short bf16x8 __attribute__((ext_vector_type(8)));
typedef float f32x4  __attribute__((ext_vector_type(4)));

__device__ __forceinline__ short f2bf(float f) {
    union { float f; unsigned u; } v; v.f = f;
    unsigned r = v.u + 0x7FFFu + ((v.u >> 16) & 1u);   // RTNE
    return (short)(r >> 16);
}

// W [512][640] f32 -> wpk fragment-packed bf16 (640 KB).
// frag gid = ((g*16+ts)*20 + tt16)*64 + kq*16 + l15, elem e = w[ts*32+kq*8+e][g*320+tt16*16+l15]
__global__ __launch_bounds__(256) void wprep(const float* __restrict__ w,
                                             short* __restrict__ wpk) {
    int gid = blockIdx.x * 256 + threadIdx.x;       // 40960 fragments
    int l15 = gid & 15, kq = (gid >> 4) & 3;
    int rem = gid >> 6;
    int tt16 = rem % 20; rem /= 20;
    int ts = rem & 15, g = rem >> 4;
    int n  = g * V_ + tt16 * 16 + l15;
    int k0 = ts * 32 + kq * 8;
    bf16x8 o;
    #pragma unroll
    for (int e = 0; e < 8; ++e) o[e] = f2bf(w[(size_t)(k0 + e) * NCOLS + n]);
    *(bf16x8*)&wpk[(size_t)gid * 8] = o;
}

// Block = 32 rows x 640 cols, 512 thr = 8 waves; wave cg owns cols cg*80..+80 (g=cg>>2).
// Swapped MFMA: D[n][m] = mfma(Wfrag, Hfrag).
// K-loop: strict issue-batch(ts+1) THEN consume-batch(ts) ordering, so the
// compiler's s_waitcnt at first consume is vmcnt(9) (one full iteration of
// slack) -- nothing forces a drain of the prefetch stream.
__global__ __launch_bounds__(512, 4) void gvq_gemm(
    const float* __restrict__ hidden,    // [32768][512] f32
    const float* __restrict__ gumbel_u,  // [65536][320] f32
    const short* __restrict__ wpk,       // fragment-packed bf16
    const float* __restrict__ bias,      // [640]
    const float* __restrict__ cv,        // [640][128]
    float* __restrict__ out,             // [32768][256] + perp scalar
    float* __restrict__ gavg)            // [NSLOT][640]
{
    __shared__ float s_psum[G_][4][BMR];
    __shared__ float s_bestv[G_][4][BMR];
    __shared__ int   s_besti[G_][4][BMR];

    const int t    = threadIdx.x;
    const int wave = t >> 6;
    const int lane = t & 63;
    const int l15  = lane & 15;
    const int kq   = lane >> 4;
    const int cg   = wave;               // col group: 80 cols
    const int g    = cg >> 2;
    const int tb   = (cg & 3) * 5;       // tt16 base within group g
    const int m0   = blockIdx.x * BMR;

    const float* hp0 = hidden + (size_t)(m0 + l15) * CDIM + kq * 8;        // rows mf=0
    const float* hp1 = hp0 + (size_t)16 * CDIM;                            // rows mf=1
    const short* wbase = wpk + ((size_t)(g * 16) * 20 + tb) * 512 + (size_t)lane * 8;

    f32x4 acc[5][2];                     // [nf][mf]
    #pragma unroll
    for (int nf = 0; nf < 5; ++nf)
        #pragma unroll
        for (int mf = 0; mf < 2; ++mf)
            #pragma unroll
            for (int r = 0; r < 4; ++r) acc[nf][mf][r] = 0.f;

    // double-buffered register batches (indices become compile-time via full unroll)
    bf16x8 bwb[2][5];
    float4 hbf[2][4];

    // prologue: issue batch ts=0 into buffer 0
    #pragma unroll
    for (int nf = 0; nf < 5; ++nf) bwb[0][nf] = *(const bf16x8*)(wbase + nf * 512);
    hbf[0][0] = *(const float4*)(hp0);
    hbf[0][1] = *(const float4*)(hp0 + 4);
    hbf[0][2] = *(const float4*)(hp1);
    hbf[0][3] = *(const float4*)(hp1 + 4);

    #pragma unroll
    for (int ts = 0; ts < 16; ++ts) {
        const int cur = ts & 1, nxt = cur ^ 1;
        // ---- issue ALL loads for ts+1 first (W then H) ----
        if (ts < 15) {
            const short* wn = wbase + (ts + 1) * 10240;
            #pragma unroll
            for (int nf = 0; nf < 5; ++nf)
                bwb[nxt][nf] = *(const bf16x8*)(wn + nf * 512);
            hbf[nxt][0] = *(const float4*)(hp0 + (ts + 1) * 32);
            hbf[nxt][1] = *(const float4*)(hp0 + (ts + 1) * 32 + 4);
            hbf[nxt][2] = *(const float4*)(hp1 + (ts + 1) * 32);
            hbf[nxt][3] = *(const float4*)(hp1 + (ts + 1) * 32 + 4);
        }
        // ---- consume batch ts (loaded one iteration ago) ----
        bf16x8 hf0, hf1;
        hf0[0]=f2bf(hbf[cur][0].x); hf0[1]=f2bf(hbf[cur][0].y);
        hf0[2]=f2bf(hbf[cur][0].z); hf0[3]=f2bf(hbf[cur][0].w);
        hf0[4]=f2bf(hbf[cur][1].x); hf0[5]=f2bf(hbf[cur][1].y);
        hf0[6]=f2bf(hbf[cur][1].z); hf0[7]=f2bf(hbf[cur][1].w);
        hf1[0]=f2bf(hbf[cur][2].x); hf1[1]=f2bf(hbf[cur][2].y);
        hf1[2]=f2bf(hbf[cur][2].z); hf1[3]=f2bf(hbf[cur][2].w);
        hf1[4]=f2bf(hbf[cur][3].x); hf1[5]=f2bf(hbf[cur][3].y);
        hf1[6]=f2bf(hbf[cur][3].z); hf1[7]=f2bf(hbf[cur][3].w);
        #pragma unroll
        for (int nf = 0; nf < 5; ++nf)
            acc[nf][0] = __builtin_amdgcn_mfma_f32_16x16x32_bf16(bwb[cur][nf], hf0, acc[nf][0], 0, 0, 0);
        #pragma unroll
        for (int nf = 0; nf < 5; ++nf)
            acc[nf][1] = __builtin_amdgcn_mfma_f32_16x16x32_bf16(bwb[cur][nf], hf1, acc[nf][1], 0, 0, 0);
    }

    // ---- epilogue (lane owns rows m0+mf*16+l15, cols g*320+(tb+nf)*16+kq*4+r) ----
    float4 bv4[5];
    #pragma unroll
    for (int nf = 0; nf < 5; ++nf)
        bv4[nf] = *(const float4*)&bias[g * V_ + (tb + nf) * 16 + kq * 4];

    #pragma unroll
    for (int mf = 0; mf < 2; ++mf) {
        const int row = m0 + mf * 16 + l15;
        const float* up = gumbel_u + ((size_t)row * G_ + g) * V_;
        // issue all 5 gumbel loads up-front
        float4 u4[5];
        #pragma unroll
        for (int nf = 0; nf < 5; ++nf)
            u4[nf] = *(const float4*)&up[(tb + nf) * 16 + kq * 4];
        float s = 0.f, best = -1e30f; int bi = 0;
        #pragma unroll
        for (int nf = 0; nf < 5; ++nf) {
            #pragma unroll
            for (int r = 0; r < 4; ++r) {
                float z = fminf(acc[nf][mf][r] + bv4[nf][r], 60.f);
                float e = __expf(z);
                acc[nf][mf][r] = e;                        // keep numerator for cp
                s += e;
                float u = (r == 0) ? u4[nf].x : (r == 1) ? u4[nf].y : (r == 2) ? u4[nf].z : u4[nf].w;
                float wv = -__logf(u + 1e-10f) + 1e-10f;
                float ratio = e * __builtin_amdgcn_rcpf(wv);  // argmax(z+gumbel)==argmax e/wv
                const int vi = (tb + nf) * 16 + kq * 4 + r;   // ascending scan -> first-max
                if (ratio > best) { best = ratio; bi = vi; }
            }
        }
        // reduce across kq groups (cols): lanes l15, l15+16, l15+32, l15+48
        #pragma unroll
        for (int o = 16; o <= 32; o <<= 1) {
            s += __shfl_xor(s, o);
            float ov = __shfl_xor(best, o);
            int   oi = __shfl_xor(bi, o);
            if (ov > best || (ov == best && oi < bi)) { best = ov; bi = oi; }
        }
        if (kq == 0) {                       // lanes 0..15
            s_psum[g][cg & 3][mf * 16 + l15]  = s;
            s_bestv[g][cg & 3][mf * 16 + l15] = best;
            s_besti[g][cg & 3][mf * 16 + l15] = bi;
        }
    }
    __syncthreads();

    // ---- cp: per-lane e*inv summed over its 2 rows, fold l15, atomics (1 per col) ----
    float inv[2];
    #pragma unroll
    for (int mf = 0; mf < 2; ++mf) {
        const int rl = mf * 16 + l15;
        inv[mf] = 1.f / (s_psum[g][0][rl] + s_psum[g][1][rl] +
                         s_psum[g][2][rl] + s_psum[g][3][rl]);
    }
    float cpl[5][4];
    #pragma unroll
    for (int nf = 0; nf < 5; ++nf)
        #pragma unroll
        for (int r = 0; r < 4; ++r) {
            float v = acc[nf][0][r] * inv[0] + acc[nf][1][r] * inv[1];
            #pragma unroll
            for (int o = 1; o <= 8; o <<= 1) v += __shfl_xor(v, o);
            cpl[nf][r] = v;
        }
    float* gslot = gavg + (size_t)(blockIdx.x & (NSLOT - 1)) * NCOLS;
    if (l15 == 0) {
        #pragma unroll
        for (int nf = 0; nf < 5; ++nf)
            #pragma unroll
            for (int r = 0; r < 4; ++r)
                atomicAdd(&gslot[g * V_ + (tb + nf) * 16 + kq * 4 + r], cpl[nf][r]);
    }

    // ---- winner finalize + codevector gather: 64 (row,g) tasks, 8 threads each ----
    {
        const int task = t >> 3;             // 0..63
        const int seg  = t & 7;
        const int r_   = task >> 1, gg = task & 1;
        float best = s_bestv[gg][0][r_]; int bi = s_besti[gg][0][r_];
        #pragma unroll
        for (int q = 1; q < 4; ++q) {
            float v = s_bestv[gg][q][r_];
            if (v > best) { best = v; bi = s_besti[gg][q][r_]; }
        }
        const float* src = cv + ((size_t)gg * V_ + bi) * DCODE + seg * 16;
        float* dst = out + (size_t)(m0 + r_) * (G_ * DCODE) + gg * DCODE + seg * 16;
        #pragma unroll
        for (int j = 0; j < 4; ++j)
            *(float4*)(dst + j * 4) = *(const float4*)(src + j * 4);
    }
}

// 1024-thr single block: phase1 threads<640 fold 64 slots (8-deep unrolled batches),
// phase2 wave 0 reduces plogp.
__global__ __launch_bounds__(1024) void gvq_perp(const float* __restrict__ gavg,
                                                 float* __restrict__ out)
{
    __shared__ float sp[NCOLS];
    const int t = threadIdx.x;
    if (t < NCOLS) {
        float a = 0.f;
        #pragma unroll
        for (int sb = 0; sb < 8; ++sb) {
            float p[8];
            #pragma unroll
            for (int j = 0; j < 8; ++j)
                p[j] = gavg[(size_t)(sb * 8 + j) * NCOLS + t];
            #pragma unroll
            for (int j = 0; j < 8; ++j) a += p[j];
        }
        sp[t] = a;
    }
    __syncthreads();
    if (t < 64) {
        float s0 = 0.f, s1 = 0.f;
        #pragma unroll
        for (int j = 0; j < 5; ++j) {
            float p0 = sp[t + j * 64]      * (1.f / NROWS);
            float p1 = sp[V_ + t + j * 64] * (1.f / NROWS);
            s0 += p0 * __logf(p0 + 1e-7f);
            s1 += p1 * __logf(p1 + 1e-7f);
        }
        #pragma unroll
        for (int o = 1; o < 64; o <<= 1) {
            s0 += __shfl_xor(s0, o);
            s1 += __shfl_xor(s1, o);
        }
        if (t == 0)
            out[(size_t)NROWS * (G_ * DCODE)] = expf(-s0) + expf(-s1);
    }
}

extern "C" void kernel_launch(void* const* d_in, const int* in_sizes, int n_in,
                              void* d_out, int out_size, void* d_ws, size_t ws_size,
                              hipStream_t stream)
{
    const float* hidden = (const float*)d_in[0];
    const float* gu     = (const float*)d_in[1];
    const float* w      = (const float*)d_in[2];
    const float* b      = (const float*)d_in[3];
    const float* cv     = (const float*)d_in[4];
    float* out  = (float*)d_out;
    float* gavg = (float*)d_ws;                       // [NSLOT][640] f32 = 160 KB
    short* wpk  = (short*)((char*)d_ws + 163840);     // 640 KB fragment-packed W

    hipMemsetAsync(d_ws, 0, NSLOT * NCOLS * sizeof(float), stream);
    wprep<<<160, 256, 0, stream>>>(w, wpk);
    gvq_gemm<<<NROWS / BMR, 512, 0, stream>>>(hidden, gu, wpk, b, cv, out, gavg);
    gvq_perp<<<1, 1024, 0, stream>>>(gavg, out);
}

// Round 14
// 117.221 us; speedup vs baseline: 1.6821x; 1.0089x over previous
//
#include <hip/hip_runtime.h>
#include <math.h>

#define NROWS 32768
#define CDIM  512
#define G_    2
#define V_    320
#define NCOLS 640
#define DCODE 128
#define NSLOT 64
#define BMR   32   // rows per block

typedef short bf16x8 __attribute__((ext_vector_type(8)));
typedef float f32x4  __attribute__((ext_vector_type(4)));

__device__ __forceinline__ short f2bf(float f) {
    union { float f; unsigned u; } v; v.f = f;
    unsigned r = v.u + 0x7FFFu + ((v.u >> 16) & 1u);   // RTNE
    return (short)(r >> 16);
}

// W [512][640] f32 -> wpk fragment-packed bf16 (640 KB).
// frag gid = ((g*16+ts)*20 + tt16)*64 + kq*16 + l15, elem e = w[ts*32+kq*8+e][g*320+tt16*16+l15]
__global__ __launch_bounds__(256) void wprep(const float* __restrict__ w,
                                             short* __restrict__ wpk) {
    int gid = blockIdx.x * 256 + threadIdx.x;       // 40960 fragments
    int l15 = gid & 15, kq = (gid >> 4) & 3;
    int rem = gid >> 6;
    int tt16 = rem % 20; rem /= 20;
    int ts = rem & 15, g = rem >> 4;
    int n  = g * V_ + tt16 * 16 + l15;
    int k0 = ts * 32 + kq * 8;
    bf16x8 o;
    #pragma unroll
    for (int e = 0; e < 8; ++e) o[e] = f2bf(w[(size_t)(k0 + e) * NCOLS + n]);
    *(bf16x8*)&wpk[(size_t)gid * 8] = o;
}

// Block = 32 rows x 640 cols, 512 thr = 8 waves; wave cg owns cols cg*80..+80 (g=cg>>2).
// Swapped MFMA: D[n][m] = mfma(Wfrag, Hfrag).
// K-loop: TRIPLE-buffered register batches, 2-ahead issue, with
// __builtin_amdgcn_sched_barrier(0) pinning the issue/consume boundary so the
// compiler cannot sink the prefetch loads to their consumers (R12 post-mortem:
// VGPR=60 proved it serialized every load at ~700cy each).
__global__ __launch_bounds__(512, 3) void gvq_gemm(
    const float* __restrict__ hidden,    // [32768][512] f32
    const float* __restrict__ gumbel_u,  // [65536][320] f32
    const short* __restrict__ wpk,       // fragment-packed bf16
    const float* __restrict__ bias,      // [640]
    const float* __restrict__ cv,        // [640][128]
    float* __restrict__ out,             // [32768][256] + perp scalar
    float* __restrict__ gavg)            // [NSLOT][640]
{
    __shared__ float s_psum[G_][4][BMR];
    __shared__ float s_bestv[G_][4][BMR];
    __shared__ int   s_besti[G_][4][BMR];

    const int t    = threadIdx.x;
    const int wave = t >> 6;
    const int lane = t & 63;
    const int l15  = lane & 15;
    const int kq   = lane >> 4;
    const int cg   = wave;               // col group: 80 cols
    const int g    = cg >> 2;
    const int tb   = (cg & 3) * 5;       // tt16 base within group g
    const int m0   = blockIdx.x * BMR;

    const float* hp0 = hidden + (size_t)(m0 + l15) * CDIM + kq * 8;        // rows mf=0
    const float* hp1 = hp0 + (size_t)16 * CDIM;                            // rows mf=1
    const short* wbase = wpk + ((size_t)(g * 16) * 20 + tb) * 512 + (size_t)lane * 8;

    f32x4 acc[5][2];                     // [nf][mf]
    #pragma unroll
    for (int nf = 0; nf < 5; ++nf)
        #pragma unroll
        for (int mf = 0; mf < 2; ++mf)
            #pragma unroll
            for (int r = 0; r < 4; ++r) acc[nf][mf][r] = 0.f;

    // triple-buffered register batches (static indices via full unroll)
    bf16x8 bwb[3][5];
    float4 hbf[3][4];

    // prologue: issue batches ts=0 -> buf0, ts=1 -> buf1
    #pragma unroll
    for (int p = 0; p < 2; ++p) {
        const short* wn = wbase + p * 10240;
        #pragma unroll
        for (int nf = 0; nf < 5; ++nf)
            bwb[p][nf] = *(const bf16x8*)(wn + nf * 512);
        hbf[p][0] = *(const float4*)(hp0 + p * 32);
        hbf[p][1] = *(const float4*)(hp0 + p * 32 + 4);
        hbf[p][2] = *(const float4*)(hp1 + p * 32);
        hbf[p][3] = *(const float4*)(hp1 + p * 32 + 4);
    }
    __builtin_amdgcn_sched_barrier(0);

    #pragma unroll
    for (int ts = 0; ts < 16; ++ts) {
        const int cur = ts % 3, nx2 = (ts + 2) % 3;
        // ---- issue batch ts+2 ----
        if (ts < 14) {
            const short* wn = wbase + (ts + 2) * 10240;
            #pragma unroll
            for (int nf = 0; nf < 5; ++nf)
                bwb[nx2][nf] = *(const bf16x8*)(wn + nf * 512);
            hbf[nx2][0] = *(const float4*)(hp0 + (ts + 2) * 32);
            hbf[nx2][1] = *(const float4*)(hp0 + (ts + 2) * 32 + 4);
            hbf[nx2][2] = *(const float4*)(hp1 + (ts + 2) * 32);
            hbf[nx2][3] = *(const float4*)(hp1 + (ts + 2) * 32 + 4);
        }
        // pin: loads above may not sink below; consumers below may not hoist above
        __builtin_amdgcn_sched_barrier(0);
        // ---- consume batch ts (issued 2 iterations ago) ----
        bf16x8 hf0, hf1;
        hf0[0]=f2bf(hbf[cur][0].x); hf0[1]=f2bf(hbf[cur][0].y);
        hf0[2]=f2bf(hbf[cur][0].z); hf0[3]=f2bf(hbf[cur][0].w);
        hf0[4]=f2bf(hbf[cur][1].x); hf0[5]=f2bf(hbf[cur][1].y);
        hf0[6]=f2bf(hbf[cur][1].z); hf0[7]=f2bf(hbf[cur][1].w);
        hf1[0]=f2bf(hbf[cur][2].x); hf1[1]=f2bf(hbf[cur][2].y);
        hf1[2]=f2bf(hbf[cur][2].z); hf1[3]=f2bf(hbf[cur][2].w);
        hf1[4]=f2bf(hbf[cur][3].x); hf1[5]=f2bf(hbf[cur][3].y);
        hf1[6]=f2bf(hbf[cur][3].z); hf1[7]=f2bf(hbf[cur][3].w);
        #pragma unroll
        for (int nf = 0; nf < 5; ++nf)
            acc[nf][0] = __builtin_amdgcn_mfma_f32_16x16x32_bf16(bwb[cur][nf], hf0, acc[nf][0], 0, 0, 0);
        #pragma unroll
        for (int nf = 0; nf < 5; ++nf)
            acc[nf][1] = __builtin_amdgcn_mfma_f32_16x16x32_bf16(bwb[cur][nf], hf1, acc[nf][1], 0, 0, 0);
    }

    // ---- epilogue (lane owns rows m0+mf*16+l15, cols g*320+(tb+nf)*16+kq*4+r) ----
    // batch-issue all epilogue loads (bias + both rows' gumbel), then fence
    float4 bv4[5], u4[2][5];
    #pragma unroll
    for (int nf = 0; nf < 5; ++nf)
        bv4[nf] = *(const float4*)&bias[g * V_ + (tb + nf) * 16 + kq * 4];
    #pragma unroll
    for (int mf = 0; mf < 2; ++mf) {
        const float* up = gumbel_u + ((size_t)(m0 + mf * 16 + l15) * G_ + g) * V_;
        #pragma unroll
        for (int nf = 0; nf < 5; ++nf)
            u4[mf][nf] = *(const float4*)&up[(tb + nf) * 16 + kq * 4];
    }
    __builtin_amdgcn_sched_barrier(0);

    #pragma unroll
    for (int mf = 0; mf < 2; ++mf) {
        float s = 0.f, best = -1e30f; int bi = 0;
        #pragma unroll
        for (int nf = 0; nf < 5; ++nf) {
            #pragma unroll
            for (int r = 0; r < 4; ++r) {
                float z = fminf(acc[nf][mf][r] + bv4[nf][r], 60.f);
                float e = __expf(z);
                acc[nf][mf][r] = e;                        // keep numerator for cp
                s += e;
                float u = (r == 0) ? u4[mf][nf].x : (r == 1) ? u4[mf][nf].y
                        : (r == 2) ? u4[mf][nf].z : u4[mf][nf].w;
                float wv = -__logf(u + 1e-10f) + 1e-10f;
                float ratio = e * __builtin_amdgcn_rcpf(wv);  // argmax(z+gumbel)==argmax e/wv
                const int vi = (tb + nf) * 16 + kq * 4 + r;   // ascending scan -> first-max
                if (ratio > best) { best = ratio; bi = vi; }
            }
        }
        // reduce across kq groups (cols): lanes l15, l15+16, l15+32, l15+48
        #pragma unroll
        for (int o = 16; o <= 32; o <<= 1) {
            s += __shfl_xor(s, o);
            float ov = __shfl_xor(best, o);
            int   oi = __shfl_xor(bi, o);
            if (ov > best || (ov == best && oi < bi)) { best = ov; bi = oi; }
        }
        if (kq == 0) {                       // lanes 0..15
            s_psum[g][cg & 3][mf * 16 + l15]  = s;
            s_bestv[g][cg & 3][mf * 16 + l15] = best;
            s_besti[g][cg & 3][mf * 16 + l15] = bi;
        }
    }
    __syncthreads();

    // ---- cp: per-lane e*inv summed over its 2 rows, fold l15, atomics (1 per col) ----
    float inv[2];
    #pragma unroll
    for (int mf = 0; mf < 2; ++mf) {
        const int rl = mf * 16 + l15;
        inv[mf] = 1.f / (s_psum[g][0][rl] + s_psum[g][1][rl] +
                         s_psum[g][2][rl] + s_psum[g][3][rl]);
    }
    float cpl[5][4];
    #pragma unroll
    for (int nf = 0; nf < 5; ++nf)
        #pragma unroll
        for (int r = 0; r < 4; ++r) {
            float v = acc[nf][0][r] * inv[0] + acc[nf][1][r] * inv[1];
            #pragma unroll
            for (int o = 1; o <= 8; o <<= 1) v += __shfl_xor(v, o);
            cpl[nf][r] = v;
        }
    float* gslot = gavg + (size_t)(blockIdx.x & (NSLOT - 1)) * NCOLS;
    if (l15 == 0) {
        #pragma unroll
        for (int nf = 0; nf < 5; ++nf)
            #pragma unroll
            for (int r = 0; r < 4; ++r)
                atomicAdd(&gslot[g * V_ + (tb + nf) * 16 + kq * 4 + r], cpl[nf][r]);
    }

    // ---- winner finalize + codevector gather: 64 (row,g) tasks, 8 threads each ----
    {
        const int task = t >> 3;             // 0..63
        const int seg  = t & 7;
        const int r_   = task >> 1, gg = task & 1;
        float best = s_bestv[gg][0][r_]; int bi = s_besti[gg][0][r_];
        #pragma unroll
        for (int q = 1; q < 4; ++q) {
            float v = s_bestv[gg][q][r_];
            if (v > best) { best = v; bi = s_besti[gg][q][r_]; }
        }
        const float* src = cv + ((size_t)gg * V_ + bi) * DCODE + seg * 16;
        float* dst = out + (size_t)(m0 + r_) * (G_ * DCODE) + gg * DCODE + seg * 16;
        #pragma unroll
        for (int j = 0; j < 4; ++j)
            *(float4*)(dst + j * 4) = *(const float4*)(src + j * 4);
    }
}

// 1024-thr single block: phase1 threads<640 fold 64 slots (8-deep unrolled batches),
// phase2 wave 0 reduces plogp.
__global__ __launch_bounds__(1024) void gvq_perp(const float* __restrict__ gavg,
                                                 float* __restrict__ out)
{
    __shared__ float sp[NCOLS];
    const int t = threadIdx.x;
    if (t < NCOLS) {
        float a = 0.f;
        #pragma unroll
        for (int sb = 0; sb < 8; ++sb) {
            float p[8];
            #pragma unroll
            for (int j = 0; j < 8; ++j)
                p[j] = gavg[(size_t)(sb * 8 + j) * NCOLS + t];
            #pragma unroll
            for (int j = 0; j < 8; ++j) a += p[j];
        }
        sp[t] = a;
    }
    __syncthreads();
    if (t < 64) {
        float s0 = 0.f, s1 = 0.f;
        #pragma unroll
        for (int j = 0; j < 5; ++j) {
            float p0 = sp[t + j * 64]      * (1.f / NROWS);
            float p1 = sp[V_ + t + j * 64] * (1.f / NROWS);
            s0 += p0 * __logf(p0 + 1e-7f);
            s1 += p1 * __logf(p1 + 1e-7f);
        }
        #pragma unroll
        for (int o = 1; o < 64; o <<= 1) {
            s0 += __shfl_xor(s0, o);
            s1 += __shfl_xor(s1, o);
        }
        if (t == 0)
            out[(size_t)NROWS * (G_ * DCODE)] = expf(-s0) + expf(-s1);
    }
}

extern "C" void kernel_launch(void* const* d_in, const int* in_sizes, int n_in,
                              void* d_out, int out_size, void* d_ws, size_t ws_size,
                              hipStream_t stream)
{
    const float* hidden = (const float*)d_in[0];
    const float* gu     = (const float*)d_in[1];
    const float* w      = (const float*)d_in[2];
    const float* b      = (const float*)d_in[3];
    const float* cv     = (const float*)d_in[4];
    float* out  = (float*)d_out;
    float* gavg = (float*)d_ws;                       // [NSLOT][640] f32 = 160 KB
    short* wpk  = (short*)((char*)d_ws + 163840);     // 640 KB fragment-packed W

    hipMemsetAsync(d_ws, 0, NSLOT * NCOLS * sizeof(float), stream);
    wprep<<<160, 256, 0, stream>>>(w, wpk);
    gvq_gemm<<<NROWS / BMR, 512, 0, stream>>>(hidden, gu, wpk, b, cv, out, gavg);
    gvq_perp<<<1, 1024, 0, stream>>>(gavg, out);
}